// Round 7
// baseline (850.250 us; speedup 1.0000x reference)
//
#include <hip/hip_runtime.h>
#include <math.h>

#define NPTS 4096
#define NS 1024
#define NK 32
#define NC 64
#define NCG 67    // 64 + 3
#define NCOUT 131 // 67 + 64
#define NB 8
#define GRID 512

typedef float v2f __attribute__((ext_vector_type(2)));
typedef unsigned long long ull;

// Full-wave (64-lane) f32 max via DPP (rocPRIM gfx9 sequence). Result returned
// wave-uniform via readlane(63).
__device__ __forceinline__ float wave_max_dpp(float v) {
  int x = __float_as_int(v);
#define DPP_STEP(ctrl)                                                        \
  {                                                                           \
    int t = __builtin_amdgcn_update_dpp(x, x, ctrl, 0xF, 0xF, false);         \
    x = __float_as_int(fmaxf(__int_as_float(x), __int_as_float(t)));          \
  }
  DPP_STEP(0x111)  // row_shr:1
  DPP_STEP(0x112)  // row_shr:2
  DPP_STEP(0x114)  // row_shr:4
  DPP_STEP(0x118)  // row_shr:8
  DPP_STEP(0x142)  // row_bcast:15
  DPP_STEP(0x143)  // row_bcast:31
#undef DPP_STEP
  return __int_as_float(__builtin_amdgcn_readlane(x, 63));
}

// Full-wave lexicographic argmin on (value asc, index asc) via DPP — pure VALU.
__device__ __forceinline__ void wave_argmin_dpp(float& v, int& i) {
#define ARG_STEP(ctrl)                                                         \
  {                                                                            \
    int tv = __builtin_amdgcn_update_dpp(__float_as_int(v), __float_as_int(v), \
                                         ctrl, 0xF, 0xF, false);               \
    int ti = __builtin_amdgcn_update_dpp(i, i, ctrl, 0xF, 0xF, false);         \
    float ov = __int_as_float(tv);                                             \
    bool t = (ov < v) || (ov == v && ti < i);                                  \
    v = t ? ov : v;                                                            \
    i = t ? ti : i;                                                            \
  }
  ARG_STEP(0x111) ARG_STEP(0x112) ARG_STEP(0x114)
  ARG_STEP(0x118) ARG_STEP(0x142) ARG_STEP(0x143)
#undef ARG_STEP
  v = __int_as_float(__builtin_amdgcn_readlane(__float_as_int(v), 63));
  i = __builtin_amdgcn_readlane(i, 63);
}

// Raw workgroup barrier that drains ONLY lgkmcnt (LDS) — keeps the relaxed
// agent-scope pick-publish store fire-and-forget (no vmcnt drain per iter).
__device__ __forceinline__ void lds_barrier() {
  asm volatile("s_waitcnt lgkmcnt(0)" ::: "memory");
  __builtin_amdgcn_s_barrier();
  asm volatile("" ::: "memory");
}

// unpack 3 float4 (12 consecutive floats) -> 4 xyz triples
__device__ __forceinline__ void unpack4(const float4* __restrict__ X4,
                                        float* px, float* py, float* pz) {
  float4 a = X4[0], c = X4[1], e = X4[2];
  px[0] = a.x; py[0] = a.y; pz[0] = a.z;
  px[1] = a.w; py[1] = c.x; pz[1] = c.y;
  px[2] = c.z; py[2] = c.w; pz[2] = e.x;
  px[3] = e.y; py[3] = e.z; pz[3] = e.w;
}

__device__ __forceinline__ void unpack16(const float4* __restrict__ X4,
                                         float* px, float* py, float* pz) {
#pragma unroll
  for (int g = 0; g < 4; ++g) unpack4(X4 + 3 * g, px + 4 * g, py + 4 * g, pz + 4 * g);
}

// ---------------- Fused kernel (regular launch; co-residency by construction:
// 70.5 KB LDS -> exactly 2 blocks/CU -> all 512 blocks resident) ----------------
// Sentinel sync (relaxed agent atomics only).
// r7 CHANGE (producer only, vs proven r4 base): the per-pick serial VALU
// structure {8-deep packed runmax accumulation chain in the distance loop +
// 16-deep cndmask recovery ladder} is replaced by a DEPTH-4 argmax tree over
// the 16 per-thread mind scalars (15 nodes x {cmp, fmax, cndmask}; value path
// uses fmax so it does not wait on the cmp). r2/r6 calibration: each serial-
// chain instruction costs ~6-10 cy here (1 busy wave/SIMD, nothing hides
// dependent latency), so chain DEPTH is what matters. Tie-break exact:
// prefer-left on >= == lowest linear index j, identical to the ladder's
// last-assignment-wins (q descending, .x over .y) semantics.
__global__ __launch_bounds__(256) void fused_kernel(const float* __restrict__ xyz,
                                                    const float* __restrict__ points,
                                                    float* __restrict__ newxyz,
                                                    int* __restrict__ fps_idx,
                                                    int* __restrict__ knn_idx,
                                                    float* __restrict__ mean_ws,
                                                    float* __restrict__ part_ws,
                                                    int* pick_idx) {
  __shared__ float4 coords4[NPTS];   // fps: winner-broadcast + output gather (64 KB)
  __shared__ int fps_lds[NS];        // fps: buffered picks (4 KB)
  __shared__ ull keys[2][4];         // fps: cross-wave keys
  __shared__ float pvv[2][4];        // knn: cross-wave values
  __shared__ int pii[2][4];          // knn: cross-wave indices
  __shared__ int idx_lds[NK];        // knn: picked neighbor indices
  __shared__ float red[256];         // knn: stats reduction
  __shared__ int gi_sh;              // knn: broadcast of polled pick

  const int tid = threadIdx.x;
  const int lane = tid & 63;
  const int wav = tid >> 6;
  const int bx = blockIdx.x;

  if (bx < NB) {
    // ================= FPS (producer) =================
#pragma clang fp contract(off)
    __builtin_amdgcn_s_setprio(3);
    const int b = bx;
    const float* X = xyz + (size_t)b * NPTS * 3;
    const int base = tid * 16;
    float px[16], py[16], pz[16];
    unpack16((const float4*)(X + (size_t)base * 3), px, py, pz);
#pragma unroll
    for (int j = 0; j < 16; ++j) coords4[base + j] = make_float4(px[j], py[j], pz[j], 0.0f);
    v2f px2[8], py2[8], pz2[8], mind2[8];
#pragma unroll
    for (int q = 0; q < 8; ++q) {
      px2[q] = v2f{px[2 * q], px[2 * q + 1]};
      py2[q] = v2f{py[2 * q], py[2 * q + 1]};
      pz2[q] = v2f{pz[2 * q], pz[2 * q + 1]};
      mind2[q] = v2f{__builtin_inff(), __builtin_inff()};
    }
    float cx = X[0], cy = X[1], cz = X[2];
    int gi = 0;
    if (tid == 0) fps_lds[0] = 0;
    __syncthreads();

    for (int s = 1; s < NS; ++s) {
      v2f cxv = v2f{cx, cx}, cyv = v2f{cy, cy}, czv = v2f{cz, cz};
      // distance + min update (packed); no serial runmax accumulation
#pragma unroll
      for (int q = 0; q < 8; ++q) {
        v2f dx = px2[q] - cxv;
        v2f dy = py2[q] - cyv;
        v2f dz = pz2[q] - czv;
        v2f d = ((dx * dx) + (dy * dy)) + (dz * dz);  // exact rn seq, no fma
        mind2[q] = __builtin_elementwise_min(mind2[q], d);
      }
      // depth-4 argmax tree over the 16 scalars (tie -> lowest index)
      float v1[8]; int i1[8];
#pragma unroll
      for (int t = 0; t < 8; ++t) {
        float a = mind2[t].x, c = mind2[t].y;
        v1[t] = fmaxf(a, c);
        i1[t] = (a >= c) ? (2 * t) : (2 * t + 1);
      }
      float v2_[4]; int i2_[4];
#pragma unroll
      for (int t = 0; t < 4; ++t) {
        float a = v1[2 * t], c = v1[2 * t + 1];
        v2_[t] = fmaxf(a, c);
        i2_[t] = (a >= c) ? i1[2 * t] : i1[2 * t + 1];
      }
      float v3_[2]; int i3_[2];
#pragma unroll
      for (int t = 0; t < 2; ++t) {
        float a = v2_[2 * t], c = v2_[2 * t + 1];
        v3_[t] = fmaxf(a, c);
        i3_[t] = (a >= c) ? i2_[2 * t] : i2_[2 * t + 1];
      }
      float bv = fmaxf(v3_[0], v3_[1]);
      int bj = (v3_[0] >= v3_[1]) ? i3_[0] : i3_[1];

      float smax = wave_max_dpp(bv);
      ull lm = __ballot(bv == smax);
      int wl = (int)(__ffsll(lm) - 1);
      int bjw = __builtin_amdgcn_readlane(bj, wl);
      int gidx = ((wav << 6) + wl) * 16 + bjw;
      ull key = ((ull)__float_as_uint(smax) << 32) |
                (ull)(0xFFFFFFFFu - (unsigned)gidx);
      const int p = s & 1;
      if (lane == 0) keys[p][wav] = key;
      lds_barrier();  // lgkm-only: publish store never drained here
      ull k0 = keys[p][0], k1 = keys[p][1], k2 = keys[p][2], k3 = keys[p][3];
      ull ka = k0 > k1 ? k0 : k1;
      ull kb = k2 > k3 ? k2 : k3;
      ull km = ka > kb ? ka : kb;
      gi = (int)(0xFFFFFFFFu - (unsigned)(km & 0xFFFFFFFFull));
      float4 c4 = coords4[gi];
      // publish pick s immediately (fire-and-forget relaxed agent store)
      if (tid == 0) {
        fps_lds[s] = gi;
        __hip_atomic_store(&pick_idx[b * NS + s], gi, __ATOMIC_RELAXED,
                           __HIP_MEMORY_SCOPE_AGENT);
      }
      cx = c4.x; cy = c4.y; cz = c4.z;
    }
    __syncthreads();
    for (int s = tid; s < NS; s += 256) {
      int g2 = fps_lds[s];
      float4 c4 = coords4[g2];
      fps_idx[b * NS + s] = g2;
      newxyz[(size_t)(b * NS + s) * 3 + 0] = c4.x;
      newxyz[(size_t)(b * NS + s) * 3 + 1] = c4.y;
      newxyz[(size_t)(b * NS + s) * 3 + 2] = c4.z;
    }
  } else {
    // ================= workers (consumers): kNN + stats per query =================
    if (bx >= 256 && bx < 256 + NB) return;  // keep fps CUs private (heuristic)
    const int w = (bx < 256) ? (bx - NB) : (bx - NB - NB);
    const int nwork = GRID - 2 * NB;         // 496 active workers
    for (int q = w; q < NB * NS; q += nwork) {
      const int b = q & 7;
      const int s = q >> 3;
      const int bs = (b << 10) | s;
      int gi = 0;
      if (s != 0) {
        // single-poller: tid 0 polls the sentinel, broadcasts via LDS.
        if (tid == 0) {
          int g = __hip_atomic_load(&pick_idx[bs], __ATOMIC_RELAXED,
                                    __HIP_MEMORY_SCOPE_AGENT);
          while (g == -1) {
            __builtin_amdgcn_s_sleep(64);
            g = __hip_atomic_load(&pick_idx[bs], __ATOMIC_RELAXED,
                                  __HIP_MEMORY_SCOPE_AGENT);
          }
          gi_sh = g;
        }
        __syncthreads();
        gi = gi_sh;
      }
      const float* X = xyz + (size_t)b * NPTS * 3;
      const float sx = X[gi * 3 + 0];   // == newxyz[bs], bitwise (copy of xyz row)
      const float sy = X[gi * 3 + 1];
      const float sz = X[gi * 3 + 2];
      const float snorm = __fadd_rn(__fadd_rn(__fmul_rn(sx, sx), __fmul_rn(sy, sy)),
                                    __fmul_rn(sz, sz));
      const int base = tid * 16;
      const float4* X4 = (const float4*)(X + (size_t)base * 3);
      float d2[16];
      float bv = __builtin_inff(); int bi = 0x7fffffff;
#pragma unroll
      for (int g4 = 0; g4 < 4; ++g4) {
        float qx[4], qy[4], qz[4];
        unpack4(X4 + 3 * g4, qx, qy, qz);
#pragma unroll
        for (int j = 0; j < 4; ++j) {
          const int jj = 4 * g4 + j;
          float nn = __fadd_rn(__fadd_rn(__fmul_rn(qx[j], qx[j]), __fmul_rn(qy[j], qy[j])),
                               __fmul_rn(qz[j], qz[j]));
          float dt = __fmaf_rn(sz, qz[j], __fmaf_rn(sy, qy[j], __fmul_rn(sx, qx[j])));
          float d = __fsub_rn(__fadd_rn(snorm, nn), __fmul_rn(2.0f, dt));
          d2[jj] = d;
          if (d < bv) { bv = d; bi = base + jj; }  // strict <: first index on ties
        }
      }
      float wv = bv; int wi = bi;
      wave_argmin_dpp(wv, wi);
      for (int k = 0; k < NK; ++k) {
        const int p = k & 1;
        if ((tid & 63) == 0) { pvv[p][wav] = wv; pii[p][wav] = wi; }
        __syncthreads();
        float gv = pvv[p][0]; int g2 = pii[p][0];
#pragma unroll
        for (int ww = 1; ww < 4; ++ww) {
          float ov = pvv[p][ww]; int oi = pii[p][ww];
          bool t = (ov < gv) || (ov == gv && oi < g2);
          if (t) { gv = ov; g2 = oi; }
        }
        if (tid == 0) idx_lds[k] = g2;
        if ((g2 >> 10) == wav) {
          if ((g2 >> 4) == tid) {
            bv = __builtin_inff(); bi = 0x7fffffff;
#pragma unroll
            for (int j = 0; j < 16; ++j) {
              float d = d2[j];
              if (base + j == g2) { d = __builtin_inff(); d2[j] = d; }
              if (d < bv) { bv = d; bi = base + j; }
            }
          }
          wv = bv; wi = bi;
          wave_argmin_dpp(wv, wi);
        }
      }
      __syncthreads();
      if (tid < NK) knn_idx[(size_t)bs * NK + tid] = idx_lds[tid];
      float acc = 0.0f;
      if (tid < NCG) {
        const float* Pb = points + (size_t)b * NPTS * NC;
        const float* Xb = xyz + (size_t)b * NPTS * 3;
        float sum = 0.0f, sumsq = 0.0f;
#pragma unroll
        for (int k = 0; k < NK; ++k) {
          int row = idx_lds[k];
          float g = (tid < NC) ? Pb[(size_t)row * NC + tid] : Xb[(size_t)row * 3 + (tid - NC)];
          sum += g;
          sumsq = __fmaf_rn(g, g, sumsq);
        }
        float m = sum * (1.0f / 32.0f);
        mean_ws[(size_t)bs * NCG + tid] = m;
        acc = __fmaf_rn(-m, sum, sumsq);
      }
      red[tid] = acc;
      __syncthreads();
      for (int off = 128; off > 0; off >>= 1) {
        if (tid < off) red[tid] += red[tid + off];
        __syncthreads();
      }
      if (tid == 0) part_ws[bs] = red[0];
      __syncthreads();
    }
  }
}

// ---------------- per-batch variance -> scale = 1/(std+1e-5) ----------------
__global__ __launch_bounds__(256) void scale_kernel(const float* __restrict__ part_ws,
                                                    float* __restrict__ scale_ws) {
  const int b = blockIdx.x;
  const int tid = threadIdx.x;
  __shared__ float red[256];
  const float* p = part_ws + (size_t)b * NS;
  float a = p[tid] + p[tid + 256] + p[tid + 512] + p[tid + 768];
  red[tid] = a;
  __syncthreads();
  for (int off = 128; off > 0; off >>= 1) {
    if (tid < off) red[tid] += red[tid + off];
    __syncthreads();
  }
  if (tid == 0) {
    float var = red[0] / 2195455.0f;  // n-1, n = 1024*32*67
    scale_ws[b] = 1.0f / (sqrtf(var) + 1e-5f);
  }
}

// ---------------- final output assembly: [B,S,K,131], float4 stores ----------------
__global__ __launch_bounds__(256) void out_kernel(const float* __restrict__ xyz,
                                                  const float* __restrict__ points,
                                                  const float* __restrict__ alpha,
                                                  const float* __restrict__ beta,
                                                  const int* __restrict__ fps_idx,
                                                  const int* __restrict__ knn_idx,
                                                  const float* __restrict__ mean_ws,
                                                  const float* __restrict__ scale_ws,
                                                  float* __restrict__ out2) {
  const int bs = blockIdx.x;
  const int b = bs >> 10;
  const int tid = threadIdx.x;
  __shared__ int idx[NK];
  __shared__ float mrow[NCG], al[NCG], be[NCG];
  __shared__ int fr_s;
  if (tid < NK) idx[tid] = knn_idx[(size_t)bs * NK + tid];
  if (tid < NCG) {
    mrow[tid] = mean_ws[(size_t)bs * NCG + tid];
    al[tid] = alpha[tid];
    be[tid] = beta[tid];
  }
  if (tid == 0) fr_s = fps_idx[bs];
  __syncthreads();
  const float scl = scale_ws[b];
  const int fr = fr_s;
  const float* Pb = points + (size_t)b * NPTS * NC;
  const float* Xb = xyz + (size_t)b * NPTS * 3;
  float* orow = out2 + (size_t)bs * NK * NCOUT;   // 4192 floats, 16B-aligned
  const float* Fr = Pb + (size_t)fr * NC;
  for (int e4 = tid; e4 < NK * NCOUT / 4; e4 += 256) {
    float4 v4;
    float* vp = &v4.x;
#pragma unroll
    for (int j = 0; j < 4; ++j) {
      int e = 4 * e4 + j;
      int k = e / NCOUT;
      int c = e - k * NCOUT;
      float v;
      if (c < NCG) {
        int row = idx[k];
        float gv = (c < NC) ? Pb[(size_t)row * NC + c] : Xb[(size_t)row * 3 + (c - NC)];
        v = (gv - mrow[c]) * scl * al[c] + be[c];
      } else {
        v = Fr[c - NCG];
      }
      vp[j] = v;
    }
    ((float4*)orow)[e4] = v4;
  }
}

extern "C" void kernel_launch(void* const* d_in, const int* in_sizes, int n_in,
                              void* d_out, int out_size, void* d_ws, size_t ws_size,
                              hipStream_t stream) {
  const float* xyz    = (const float*)d_in[0];
  const float* points = (const float*)d_in[1];
  const float* alpha  = (const float*)d_in[2];
  const float* beta   = (const float*)d_in[3];

  float* out = (float*)d_out;
  float* newxyz = out;                       // B*S*3 = 24576 floats
  float* out2 = out + (size_t)NB * NS * 3;   // B*S*K*131 floats

  char* ws = (char*)d_ws;
  int*   fps_idx  = (int*)(ws + 0);          //   32768 B
  int*   knn_idx  = (int*)(ws + 32768);      // 1048576 B
  float* mean_ws  = (float*)(ws + 1081344);  // 2195456 B
  float* part_ws  = (float*)(ws + 3276800);  //   32768 B
  float* scale_ws = (float*)(ws + 3309568);  //      64 B
  int*   pick_idx = (int*)(ws + 3309632);    //   32768 B (sentinel-sync picks)

  hipMemsetAsync(pick_idx, 0xFF, NB * NS * sizeof(int), stream);

  fused_kernel<<<GRID,    256, 0, stream>>>(xyz, points, newxyz, fps_idx, knn_idx,
                                            mean_ws, part_ws, pick_idx);
  scale_kernel<<<NB,      256, 0, stream>>>(part_ws, scale_ws);
  out_kernel  <<<NB * NS, 256, 0, stream>>>(xyz, points, alpha, beta, fps_idx, knn_idx,
                                            mean_ws, scale_ws, out2);
}

// Round 8
// 656.586 us; speedup vs baseline: 1.2950x; 1.2950x over previous
//
#include <hip/hip_runtime.h>
#include <math.h>

#define NPTS 4096
#define NS 1024
#define NK 32
#define NC 64
#define NCG 67    // 64 + 3
#define NCOUT 131 // 67 + 64
#define NB 8
#define GRID 512

typedef float v2f __attribute__((ext_vector_type(2)));
typedef unsigned long long ull;

// Full-wave (64-lane) f32 max via DPP (rocPRIM gfx9 sequence). Result returned
// wave-uniform via readlane(63).
__device__ __forceinline__ float wave_max_dpp(float v) {
  int x = __float_as_int(v);
#define DPP_STEP(ctrl)                                                        \
  {                                                                           \
    int t = __builtin_amdgcn_update_dpp(x, x, ctrl, 0xF, 0xF, false);         \
    x = __float_as_int(fmaxf(__int_as_float(x), __int_as_float(t)));          \
  }
  DPP_STEP(0x111)  // row_shr:1
  DPP_STEP(0x112)  // row_shr:2
  DPP_STEP(0x114)  // row_shr:4
  DPP_STEP(0x118)  // row_shr:8
  DPP_STEP(0x142)  // row_bcast:15
  DPP_STEP(0x143)  // row_bcast:31
#undef DPP_STEP
  return __int_as_float(__builtin_amdgcn_readlane(x, 63));
}

// Full-wave lexicographic argmin on (value asc, index asc) via DPP — pure VALU.
__device__ __forceinline__ void wave_argmin_dpp(float& v, int& i) {
#define ARG_STEP(ctrl)                                                         \
  {                                                                            \
    int tv = __builtin_amdgcn_update_dpp(__float_as_int(v), __float_as_int(v), \
                                         ctrl, 0xF, 0xF, false);               \
    int ti = __builtin_amdgcn_update_dpp(i, i, ctrl, 0xF, 0xF, false);         \
    float ov = __int_as_float(tv);                                             \
    bool t = (ov < v) || (ov == v && ti < i);                                  \
    v = t ? ov : v;                                                            \
    i = t ? ti : i;                                                            \
  }
  ARG_STEP(0x111) ARG_STEP(0x112) ARG_STEP(0x114)
  ARG_STEP(0x118) ARG_STEP(0x142) ARG_STEP(0x143)
#undef ARG_STEP
  v = __int_as_float(__builtin_amdgcn_readlane(__float_as_int(v), 63));
  i = __builtin_amdgcn_readlane(i, 63);
}

// Raw workgroup barrier that drains ONLY lgkmcnt (LDS) — the per-iteration FPS
// barrier must NOT drain vmcnt: the pick-publish global store (agent-scope,
// relaxed) is fire-and-forget, and __syncthreads()'s mandatory
// s_waitcnt vmcnt(0) would put the cross-XCD store-ack latency on the serial
// FPS critical path every iteration. keys[] is parity-double-buffered, so one
// barrier per iteration with lgkm-only semantics is sufficient (writes to
// parity p never clobber in-flight reads of parity p^1).
__device__ __forceinline__ void lds_barrier() {
  asm volatile("s_waitcnt lgkmcnt(0)" ::: "memory");  // own ds_write visible
  __builtin_amdgcn_s_barrier();
  asm volatile("" ::: "memory");                      // no load hoist above bar
}

// unpack 3 float4 (12 consecutive floats) -> 4 xyz triples
__device__ __forceinline__ void unpack4(const float4* __restrict__ X4,
                                        float* px, float* py, float* pz) {
  float4 a = X4[0], c = X4[1], e = X4[2];
  px[0] = a.x; py[0] = a.y; pz[0] = a.z;
  px[1] = a.w; py[1] = c.x; pz[1] = c.y;
  px[2] = c.z; py[2] = c.w; pz[2] = e.x;
  px[3] = e.y; py[3] = e.z; pz[3] = e.w;
}

__device__ __forceinline__ void unpack16(const float4* __restrict__ X4,
                                         float* px, float* py, float* pz) {
#pragma unroll
  for (int g = 0; g < 4; ++g) unpack4(X4 + 3 * g, px + 4 * g, py + 4 * g, pz + 4 * g);
}

// ---------------- Fused kernel (regular launch; co-residency by construction:
// 70.5 KB LDS -> exactly 2 blocks/CU -> all 512 blocks resident) ----------------
// Sentinel sync (relaxed agent atomics only — no fences/invalidates).
// This is the session's best measured configuration (r1: fused 607 us, total
// 657 us). Rounds 2-7 falsified, in order: issue-starvation (8-wave producer,
// -65 us), candidate-cache epochs (-160 us), poller contention (neutral),
// CU-mate mapping + barrier-skew (neutral/-10), LDS-trip removal via coord
// exchange (-140 us), argmax-tree depth reduction (-186 us). Conclusion: the
// r1 producer body is a strong local optimum; per-pick cost (~594 ns) is a
// serial dependent chain whose measured cost runs ~2x the 2.4 GHz issue+latency
// model (suspect: effective clock on this near-idle dispatch), so every added
// chain instruction costs ~6-10 "apparent" cycles and removals of latency buy
// less than their instruction cost. Do not perturb without new counter evidence.
__global__ __launch_bounds__(256) void fused_kernel(const float* __restrict__ xyz,
                                                    const float* __restrict__ points,
                                                    float* __restrict__ newxyz,
                                                    int* __restrict__ fps_idx,
                                                    int* __restrict__ knn_idx,
                                                    float* __restrict__ mean_ws,
                                                    float* __restrict__ part_ws,
                                                    int* pick_idx) {
  __shared__ float4 coords4[NPTS];   // fps: winner-broadcast + output gather (64 KB)
  __shared__ int fps_lds[NS];        // fps: buffered picks (4 KB)
  __shared__ ull keys[2][4];         // fps: cross-wave keys
  __shared__ float pvv[2][4];        // knn: cross-wave values
  __shared__ int pii[2][4];          // knn: cross-wave indices
  __shared__ int idx_lds[NK];        // knn: picked neighbor indices
  __shared__ float red[256];         // knn: stats reduction

  const int tid = threadIdx.x;
  const int lane = tid & 63;
  const int wav = tid >> 6;
  const int bx = blockIdx.x;

  if (bx < NB) {
    // ================= FPS (producer; round-1 body) =================
#pragma clang fp contract(off)
    __builtin_amdgcn_s_setprio(3);
    const int b = bx;
    const float* X = xyz + (size_t)b * NPTS * 3;
    const int base = tid * 16;
    float px[16], py[16], pz[16];
    unpack16((const float4*)(X + (size_t)base * 3), px, py, pz);
#pragma unroll
    for (int j = 0; j < 16; ++j) coords4[base + j] = make_float4(px[j], py[j], pz[j], 0.0f);
    v2f px2[8], py2[8], pz2[8], mind2[8];
#pragma unroll
    for (int q = 0; q < 8; ++q) {
      px2[q] = v2f{px[2 * q], px[2 * q + 1]};
      py2[q] = v2f{py[2 * q], py[2 * q + 1]};
      pz2[q] = v2f{pz[2 * q], pz[2 * q + 1]};
      mind2[q] = v2f{__builtin_inff(), __builtin_inff()};
    }
    float cx = X[0], cy = X[1], cz = X[2];
    int gi = 0;
    if (tid == 0) fps_lds[0] = 0;
    __syncthreads();

    for (int s = 1; s < NS; ++s) {
      v2f cxv = v2f{cx, cx}, cyv = v2f{cy, cy}, czv = v2f{cz, cz};
      v2f runmax = v2f{-1.0f, -1.0f};
#pragma unroll
      for (int q = 0; q < 8; ++q) {
        v2f dx = px2[q] - cxv;
        v2f dy = py2[q] - cyv;
        v2f dz = pz2[q] - czv;
        v2f d = ((dx * dx) + (dy * dy)) + (dz * dz);  // exact rn seq, no fma
        v2f m = __builtin_elementwise_min(mind2[q], d);
        mind2[q] = m;
        runmax = __builtin_elementwise_max(runmax, m);
      }
      float bv = fmaxf(runmax.x, runmax.y);
      int bj = 0;
#pragma unroll
      for (int q = 7; q >= 0; --q) {
        bj = (mind2[q].y == bv) ? 2 * q + 1 : bj;
        bj = (mind2[q].x == bv) ? 2 * q : bj;
      }
      float smax = wave_max_dpp(bv);
      ull lm = __ballot(bv == smax);
      int wl = (int)(__ffsll(lm) - 1);
      int bjw = __builtin_amdgcn_readlane(bj, wl);
      int gidx = ((wav << 6) + wl) * 16 + bjw;
      ull key = ((ull)__float_as_uint(smax) << 32) |
                (ull)(0xFFFFFFFFu - (unsigned)gidx);
      const int p = s & 1;
      if (lane == 0) keys[p][wav] = key;
      lds_barrier();  // lgkm-only: publish store never drained here
      ull k0 = keys[p][0], k1 = keys[p][1], k2 = keys[p][2], k3 = keys[p][3];
      ull ka = k0 > k1 ? k0 : k1;
      ull kb = k2 > k3 ? k2 : k3;
      ull km = ka > kb ? ka : kb;
      gi = (int)(0xFFFFFFFFu - (unsigned)(km & 0xFFFFFFFFull));
      float4 c4 = coords4[gi];
      // publish pick s immediately (fire-and-forget relaxed agent store; its
      // ack latency is fully off the critical path)
      if (tid == 0) {
        fps_lds[s] = gi;
        __hip_atomic_store(&pick_idx[b * NS + s], gi, __ATOMIC_RELAXED,
                           __HIP_MEMORY_SCOPE_AGENT);
      }
      cx = c4.x; cy = c4.y; cz = c4.z;
    }
    __syncthreads();
    for (int s = tid; s < NS; s += 256) {
      int g2 = fps_lds[s];
      float4 c4 = coords4[g2];
      fps_idx[b * NS + s] = g2;
      newxyz[(size_t)(b * NS + s) * 3 + 0] = c4.x;
      newxyz[(size_t)(b * NS + s) * 3 + 1] = c4.y;
      newxyz[(size_t)(b * NS + s) * 3 + 2] = c4.z;
    }
  } else {
    // ================= workers (consumers): kNN + stats per query =================
    if (bx >= 256 && bx < 256 + NB) return;  // keep fps CUs private (heuristic)
    const int w = (bx < 256) ? (bx - NB) : (bx - NB - NB);
    const int nwork = GRID - 2 * NB;         // 496 active workers
    for (int q = w; q < NB * NS; q += nwork) {
      const int b = q & 7;
      const int s = q >> 3;
      const int bs = (b << 10) | s;
      int gi = 0;
      if (s != 0) {
        gi = __hip_atomic_load(&pick_idx[bs], __ATOMIC_RELAXED, __HIP_MEMORY_SCOPE_AGENT);
        while (gi == -1) {
          __builtin_amdgcn_s_sleep(16);
          gi = __hip_atomic_load(&pick_idx[bs], __ATOMIC_RELAXED, __HIP_MEMORY_SCOPE_AGENT);
        }
      }
      const float* X = xyz + (size_t)b * NPTS * 3;
      const float sx = X[gi * 3 + 0];   // == newxyz[bs], bitwise (copy of xyz row)
      const float sy = X[gi * 3 + 1];
      const float sz = X[gi * 3 + 2];
      const float snorm = __fadd_rn(__fadd_rn(__fmul_rn(sx, sx), __fmul_rn(sy, sy)),
                                    __fmul_rn(sz, sz));
      const int base = tid * 16;
      const float4* X4 = (const float4*)(X + (size_t)base * 3);
      float d2[16];
      float bv = __builtin_inff(); int bi = 0x7fffffff;
#pragma unroll
      for (int g4 = 0; g4 < 4; ++g4) {
        float qx[4], qy[4], qz[4];
        unpack4(X4 + 3 * g4, qx, qy, qz);
#pragma unroll
        for (int j = 0; j < 4; ++j) {
          const int jj = 4 * g4 + j;
          float nn = __fadd_rn(__fadd_rn(__fmul_rn(qx[j], qx[j]), __fmul_rn(qy[j], qy[j])),
                               __fmul_rn(qz[j], qz[j]));
          float dt = __fmaf_rn(sz, qz[j], __fmaf_rn(sy, qy[j], __fmul_rn(sx, qx[j])));
          float d = __fsub_rn(__fadd_rn(snorm, nn), __fmul_rn(2.0f, dt));
          d2[jj] = d;
          if (d < bv) { bv = d; bi = base + jj; }  // strict <: first index on ties
        }
      }
      float wv = bv; int wi = bi;
      wave_argmin_dpp(wv, wi);
      for (int k = 0; k < NK; ++k) {
        const int p = k & 1;
        if ((tid & 63) == 0) { pvv[p][wav] = wv; pii[p][wav] = wi; }
        __syncthreads();
        float gv = pvv[p][0]; int g2 = pii[p][0];
#pragma unroll
        for (int ww = 1; ww < 4; ++ww) {
          float ov = pvv[p][ww]; int oi = pii[p][ww];
          bool t = (ov < gv) || (ov == gv && oi < g2);
          if (t) { gv = ov; g2 = oi; }
        }
        if (tid == 0) idx_lds[k] = g2;
        if ((g2 >> 10) == wav) {
          if ((g2 >> 4) == tid) {
            bv = __builtin_inff(); bi = 0x7fffffff;
#pragma unroll
            for (int j = 0; j < 16; ++j) {
              float d = d2[j];
              if (base + j == g2) { d = __builtin_inff(); d2[j] = d; }
              if (d < bv) { bv = d; bi = base + j; }
            }
          }
          wv = bv; wi = bi;
          wave_argmin_dpp(wv, wi);
        }
      }
      __syncthreads();
      if (tid < NK) knn_idx[(size_t)bs * NK + tid] = idx_lds[tid];
      float acc = 0.0f;
      if (tid < NCG) {
        const float* Pb = points + (size_t)b * NPTS * NC;
        const float* Xb = xyz + (size_t)b * NPTS * 3;
        float sum = 0.0f, sumsq = 0.0f;
#pragma unroll
        for (int k = 0; k < NK; ++k) {
          int row = idx_lds[k];
          float g = (tid < NC) ? Pb[(size_t)row * NC + tid] : Xb[(size_t)row * 3 + (tid - NC)];
          sum += g;
          sumsq = __fmaf_rn(g, g, sumsq);
        }
        float m = sum * (1.0f / 32.0f);
        mean_ws[(size_t)bs * NCG + tid] = m;
        acc = __fmaf_rn(-m, sum, sumsq);
      }
      red[tid] = acc;
      __syncthreads();
      for (int off = 128; off > 0; off >>= 1) {
        if (tid < off) red[tid] += red[tid + off];
        __syncthreads();
      }
      if (tid == 0) part_ws[bs] = red[0];
      __syncthreads();
    }
  }
}

// ---------------- per-batch variance -> scale = 1/(std+1e-5) ----------------
__global__ __launch_bounds__(256) void scale_kernel(const float* __restrict__ part_ws,
                                                    float* __restrict__ scale_ws) {
  const int b = blockIdx.x;
  const int tid = threadIdx.x;
  __shared__ float red[256];
  const float* p = part_ws + (size_t)b * NS;
  float a = p[tid] + p[tid + 256] + p[tid + 512] + p[tid + 768];
  red[tid] = a;
  __syncthreads();
  for (int off = 128; off > 0; off >>= 1) {
    if (tid < off) red[tid] += red[tid + off];
    __syncthreads();
  }
  if (tid == 0) {
    float var = red[0] / 2195455.0f;  // n-1, n = 1024*32*67
    scale_ws[b] = 1.0f / (sqrtf(var) + 1e-5f);
  }
}

// ---------------- final output assembly: [B,S,K,131], float4 stores ----------------
__global__ __launch_bounds__(256) void out_kernel(const float* __restrict__ xyz,
                                                  const float* __restrict__ points,
                                                  const float* __restrict__ alpha,
                                                  const float* __restrict__ beta,
                                                  const int* __restrict__ fps_idx,
                                                  const int* __restrict__ knn_idx,
                                                  const float* __restrict__ mean_ws,
                                                  const float* __restrict__ scale_ws,
                                                  float* __restrict__ out2) {
  const int bs = blockIdx.x;
  const int b = bs >> 10;
  const int tid = threadIdx.x;
  __shared__ int idx[NK];
  __shared__ float mrow[NCG], al[NCG], be[NCG];
  __shared__ int fr_s;
  if (tid < NK) idx[tid] = knn_idx[(size_t)bs * NK + tid];
  if (tid < NCG) {
    mrow[tid] = mean_ws[(size_t)bs * NCG + tid];
    al[tid] = alpha[tid];
    be[tid] = beta[tid];
  }
  if (tid == 0) fr_s = fps_idx[bs];
  __syncthreads();
  const float scl = scale_ws[b];
  const int fr = fr_s;
  const float* Pb = points + (size_t)b * NPTS * NC;
  const float* Xb = xyz + (size_t)b * NPTS * 3;
  float* orow = out2 + (size_t)bs * NK * NCOUT;   // 4192 floats, 16B-aligned
  const float* Fr = Pb + (size_t)fr * NC;
  for (int e4 = tid; e4 < NK * NCOUT / 4; e4 += 256) {
    float4 v4;
    float* vp = &v4.x;
#pragma unroll
    for (int j = 0; j < 4; ++j) {
      int e = 4 * e4 + j;
      int k = e / NCOUT;
      int c = e - k * NCOUT;
      float v;
      if (c < NCG) {
        int row = idx[k];
        float gv = (c < NC) ? Pb[(size_t)row * NC + c] : Xb[(size_t)row * 3 + (c - NC)];
        v = (gv - mrow[c]) * scl * al[c] + be[c];
      } else {
        v = Fr[c - NCG];
      }
      vp[j] = v;
    }
    ((float4*)orow)[e4] = v4;
  }
}

extern "C" void kernel_launch(void* const* d_in, const int* in_sizes, int n_in,
                              void* d_out, int out_size, void* d_ws, size_t ws_size,
                              hipStream_t stream) {
  const float* xyz    = (const float*)d_in[0];
  const float* points = (const float*)d_in[1];
  const float* alpha  = (const float*)d_in[2];
  const float* beta   = (const float*)d_in[3];

  float* out = (float*)d_out;
  float* newxyz = out;                       // B*S*3 = 24576 floats
  float* out2 = out + (size_t)NB * NS * 3;   // B*S*K*131 floats

  char* ws = (char*)d_ws;
  int*   fps_idx  = (int*)(ws + 0);          //   32768 B
  int*   knn_idx  = (int*)(ws + 32768);      // 1048576 B
  float* mean_ws  = (float*)(ws + 1081344);  // 2195456 B
  float* part_ws  = (float*)(ws + 3276800);  //   32768 B
  float* scale_ws = (float*)(ws + 3309568);  //      64 B
  int*   pick_idx = (int*)(ws + 3309632);    //   32768 B (sentinel-sync picks)

  hipMemsetAsync(pick_idx, 0xFF, NB * NS * sizeof(int), stream);

  fused_kernel<<<GRID,    256, 0, stream>>>(xyz, points, newxyz, fps_idx, knn_idx,
                                            mean_ws, part_ws, pick_idx);
  scale_kernel<<<NB,      256, 0, stream>>>(part_ws, scale_ws);
  out_kernel  <<<NB * NS, 256, 0, stream>>>(xyz, points, alpha, beta, fps_idx, knn_idx,
                                            mean_ws, scale_ws, out2);
}